// Round 8
// baseline (313.193 us; speedup 1.0000x reference)
//
#include <hip/hip_runtime.h>
#include <stdint.h>

#define B_    8
#define A_    49104
#define C_    90
#define IMG_  512.0f
#define THR_  0.2f
#define KPRE  1000
#define KOUT  100
#define NCAND 1024   // padded candidate count (power of two)
#define NKEY  2048   // per-image key buffer
#define NBIN  1024   // histogram bins (fallback path)
#define BINBASE 0x17C99u     // f2ord(0.2f) >> 15
#define THRU    0xBE4CCCCDu  // f2ord(0.2f)
#define GANCH 64     // anchors per decode block
#define PREF_F 0.9997f       // static prefilter (max of 90 uniforms)

static __device__ __forceinline__ uint32_t f2ord(float f) {
    uint32_t b = __float_as_uint(f);
    return (b & 0x80000000u) ? ~b : (b | 0x80000000u);
}
static __device__ __forceinline__ float ord2f(uint32_t u) {
    uint32_t b = (u & 0x80000000u) ? (u & 0x7FFFFFFFu) : ~u;
    return __uint_as_float(b);
}

// ---------------------------------------------------------------- kernel 1
// streaming decode: LDS-coalesced max/argmax + decode/clip + wave-aggregated
// prefilter compaction (u >= f2ord(0.9997) -> per-image global key list).
__global__ __launch_bounds__(256)
void k_score_decode(const float* __restrict__ cls,
                    const float* __restrict__ loc,
                    const float* __restrict__ anc,
                    uint32_t* __restrict__ scores_u,
                    int* __restrict__ classes,
                    float* __restrict__ boxes,
                    uint64_t* __restrict__ keysg,
                    uint32_t* __restrict__ pcnt) {
    __shared__ float4 s4[(GANCH * C_) / 4];          // 1440 float4 = 23040 B
    __shared__ float r_val[GANCH];
    __shared__ int   r_cls[GANCH];

    int tid = threadIdx.x;
    int b = blockIdx.y;
    int a0 = blockIdx.x * GANCH;
    int valid = A_ - a0; if (valid > GANCH) valid = GANCH;

    // prefetch decode inputs early (overlap with cls staging)
    float4 an, l4;
    if (tid < valid) {
        int a = a0 + tid;
        an = ((const float4*)anc)[a];
        l4 = ((const float4*)loc)[(size_t)b * A_ + a];
    }

    const float4* src = (const float4*)(cls + (size_t)(b * A_ + a0) * C_);
    if (valid == GANCH) {
        float4 v0 = src[tid];
        float4 v1 = src[tid + 256];
        float4 v2 = src[tid + 512];
        float4 v3 = src[tid + 768];
        float4 v4 = src[tid + 1024];
        float4 v5;
        if (tid < 160) v5 = src[tid + 1280];
        s4[tid]        = v0;
        s4[tid + 256]  = v1;
        s4[tid + 512]  = v2;
        s4[tid + 768]  = v3;
        s4[tid + 1024] = v4;
        if (tid < 160) s4[tid + 1280] = v5;
    } else {
        int n4 = (valid * C_) / 4;                   // valid even -> exact
        for (int i = tid; i < n4; i += 256) s4[i] = src[i];
    }
    __syncthreads();

    const float* s = (const float*)s4;
    int g = tid >> 2, sub = tid & 3;
    float best = -1.0f; int bi = 0;
    if (g < valid) {
        #pragma unroll
        for (int j = sub; j < C_ + 2; j += 4) {
            if (j < C_) {
                float v = s[g * C_ + j];
                if (v > best) { best = v; bi = j; }
            }
        }
    }
    #pragma unroll
    for (int d = 1; d < 4; d <<= 1) {
        float ov = __shfl_xor(best, d);
        int   oi = __shfl_xor(bi, d);
        if (ov > best || (ov == best && oi < bi)) { best = ov; bi = oi; }
    }
    if (sub == 0 && g < valid) { r_val[g] = best; r_cls[g] = bi; }
    __syncthreads();

    uint32_t u = 0;
    int aidx = a0 + tid;
    if (tid < valid) {
        int gid = b * A_ + aidx;
        float bv = r_val[tid];
        float m = (bv > THR_) ? bv : -1.0f;
        u = f2ord(m);
        scores_u[gid] = u;
        classes[gid]  = r_cls[tid];

        float ya = (an.x + an.z) * 0.5f;
        float xa = (an.y + an.w) * 0.5f;
        float ha = an.z - an.x;
        float wa = an.w - an.y;
        float h  = expf(l4.z) * ha;
        float w  = expf(l4.w) * wa;
        float yc = l4.x * ha + ya;
        float xc = l4.y * wa + xa;
        float4 bx;
        bx.x = fminf(fmaxf(xc - w * 0.5f, 0.0f), IMG_);
        bx.y = fminf(fmaxf(yc - h * 0.5f, 0.0f), IMG_);
        bx.z = fminf(fmaxf(xc + w * 0.5f, 0.0f), IMG_);
        bx.w = fminf(fmaxf(yc + h * 0.5f, 0.0f), IMG_);
        ((float4*)boxes)[gid] = bx;
    }

    // wave-aggregated prefilter append (only wave 0 has nonzero bits)
    const uint32_t PREF = f2ord(PREF_F);
    bool pass = (tid < valid) && (u >= PREF);
    unsigned long long mm = __ballot(pass);
    if (mm) {
        int lane = tid & 63;
        uint32_t base;
        if (lane == 0) base = atomicAdd(&pcnt[b], (uint32_t)__popcll(mm));
        base = (uint32_t)__shfl((int)base, 0);
        if (pass) {
            int p = (int)base + (int)__popcll(mm & ((1ull << lane) - 1ull));
            if (p < NKEY)
                keysg[(size_t)b * NKEY + p] =
                    ((uint64_t)u << 32) | (uint32_t)(~(uint32_t)aidx);
        }
    }
}

// ---------------------------------------------------------------- kernel 2
// per-image: load prefiltered keys (exact-histogram fallback if count
// outside [KPRE,NKEY]) -> exact rank-sort -> gather cand into LDS ->
// greedy NMS with on-the-fly IoU vs kept set -> write outputs.
__global__ __launch_bounds__(1024)
void k_sort_nms(const uint32_t* __restrict__ scores_u,
                const uint32_t* __restrict__ pcnt,
                const uint64_t* __restrict__ keysg,
                const int* __restrict__ classes,
                const float* __restrict__ boxes,
                float* __restrict__ out) {
    int b = blockIdx.x;
    int t = threadIdx.x;                  // 1024
    __shared__ uint64_t keys[NKEY];       // 16 KB
    __shared__ uint32_t h[NBIN];          // 4 KB (fallback only)
    __shared__ float4   c_box[NCAND];     // 16 KB
    __shared__ float    c_val[NCAND];     // 4 KB
    __shared__ int      c_cls[NCAND];     // 4 KB
    __shared__ float kx1[128], ky1[128], kx2[128], ky2[128], kar[128];
    __shared__ int   kidx[KOUT];
    __shared__ uint32_t sh_coarse;
    __shared__ int      sh_rem;
    __shared__ uint32_t sh_cutoff;
    __shared__ int      sh_cnt;
    const uint32_t* su = scores_u + (size_t)b * A_;

    int n = (int)pcnt[b];
    if (n >= KPRE && n <= NKEY) {
        // fast path: keys already compacted by k1
        for (int i = t; i < n; i += 1024)
            keys[i] = keysg[(size_t)b * NKEY + i];
        __syncthreads();
    } else {
        // exact fallback: coarse hist -> fine hist -> compact (from scores_u)
        h[t] = 0;
        if (t == 0) sh_cnt = 0;
        __syncthreads();
        for (int a = t; a < A_; a += 1024) {
            uint32_t u = su[a];
            if (u > THRU) {
                int bin = (int)(u >> 15) - (int)BINBASE;
                bin = bin < 0 ? 0 : (bin >= NBIN ? NBIN - 1 : bin);
                atomicAdd(&h[bin], 1u);
            }
        }
        __syncthreads();
        for (int d = 1; d < NBIN; d <<= 1) {
            uint32_t add = (t + d < NBIN) ? h[t + d] : 0u;
            __syncthreads();
            h[t] += add;
            __syncthreads();
        }
        {
            uint32_t St = h[t];
            uint32_t Sn = (t + 1 < NBIN) ? h[t + 1] : 0u;
            if (St >= KPRE && Sn < KPRE) {
                sh_coarse = (BINBASE + (uint32_t)t) << 15;
                sh_rem = KPRE - (int)Sn;
            }
            if (t == 0 && h[0] < KPRE) {
                sh_rem = 0;
                sh_coarse = 0xFFFFFFFFu;
                sh_cutoff = BINBASE << 15;
            }
        }
        __syncthreads();
        uint32_t coarse = sh_coarse;
        int rem = sh_rem;

        h[t] = 0;
        __syncthreads();
        if (rem > 0) {
            for (int a = t; a < A_; a += 1024) {
                uint32_t u = su[a];
                if ((u & 0xFFFF8000u) == coarse)
                    atomicAdd(&h[(u >> 5) & 0x3FF], 1u);
            }
        }
        __syncthreads();
        for (int d = 1; d < NBIN; d <<= 1) {
            uint32_t add = (t + d < NBIN) ? h[t + d] : 0u;
            __syncthreads();
            h[t] += add;
            __syncthreads();
        }
        if (rem > 0) {
            int St = (int)h[t];
            int Sn = (t + 1 < NBIN) ? (int)h[t + 1] : 0;
            if (St >= rem && Sn < rem)
                sh_cutoff = coarse | ((uint32_t)t << 5);
        }
        __syncthreads();
        uint32_t cutoff = sh_cutoff;

        for (int a = t; a < A_; a += 1024) {
            uint32_t u = su[a];
            if (u >= cutoff) {
                int p = atomicAdd(&sh_cnt, 1);
                if (p < NKEY)
                    keys[p] = ((uint64_t)u << 32) | (uint32_t)(~(uint32_t)a);
            }
        }
        __syncthreads();
        n = sh_cnt; if (n > NKEY) n = NKEY;
    }

    // ---- exact rank-sort (keys unique), emit top-NCAND into LDS
    uint64_t k0 = (t        < n) ? keys[t]        : 0ull;
    uint64_t k1 = (t + 1024 < n) ? keys[t + 1024] : 0ull;
    int r0 = 0, r1 = 0;
    #pragma unroll 4
    for (int j = 0; j < n; ++j) {
        uint64_t v = keys[j];
        r0 += (v > k0);
        r1 += (v > k1);
    }
    #pragma unroll
    for (int q = 0; q < 2; ++q) {
        int i = t + q * 1024;
        int r = q == 0 ? r0 : r1;
        uint64_t k = q == 0 ? k0 : k1;
        if (i < n && r < NCAND) {
            uint32_t u = (uint32_t)(k >> 32);
            int ai = (int)(~(uint32_t)k);
            c_val[r] = ord2f(u);
            c_cls[r] = classes[(size_t)b * A_ + ai];
            c_box[r] = ((const float4*)boxes)[(size_t)b * A_ + ai];
        }
    }
    int nn = n < NCAND ? n : NCAND;
    for (int i = nn + t; i < NCAND; i += 1024) {
        c_val[i] = -1.0f;
        c_cls[i] = 0;
        float4 z; z.x = z.y = z.z = z.w = 0.0f;
        c_box[i] = z;
    }
    __syncthreads();

    // ---- wave 0: greedy NMS, IoU only vs kept set (<=100 boxes)
    if (t < 64) {
        int l = t;
        int nv = n < KPRE ? n : KPRE;
        int cnt = 0;
        for (int i = 0; i < nv && cnt < KOUT; ++i) {
            float4 bx = c_box[i];                  // broadcast LDS read
            float off = (float)c_cls[i] * (IMG_ + 1.0f);
            float ix1 = bx.x + off, iy1 = bx.y + off;
            float ix2 = bx.z + off, iy2 = bx.w + off;
            float iar = (ix2 - ix1) * (iy2 - iy1); // area AFTER offset (ref)
            bool pred = false;
            #pragma unroll
            for (int q = 0; q < 2; ++q) {
                int s = l + q * 64;
                if (s < cnt) {
                    float xx1 = fmaxf(ix1, kx1[s]);
                    float yy1 = fmaxf(iy1, ky1[s]);
                    float xx2 = fminf(ix2, kx2[s]);
                    float yy2 = fminf(iy2, ky2[s]);
                    float iw = xx2 - xx1; iw = iw > 0.0f ? iw : 0.0f;
                    float ih = yy2 - yy1; ih = ih > 0.0f ? ih : 0.0f;
                    float inter = iw * ih;
                    float den = (kar[s] + iar) - inter + 1e-8f; // ref order
                    pred |= (inter / den > THR_);
                }
            }
            if (__ballot(pred) == 0ull) {
                if (l == 0) {
                    kx1[cnt] = ix1; ky1[cnt] = iy1;
                    kx2[cnt] = ix2; ky2[cnt] = iy2;
                    kar[cnt] = iar; kidx[cnt] = i;
                }
                cnt++;
            }
        }

        // ---- outputs
        for (int s_ = l; s_ < KOUT; s_ += 64) {
            float b0 = 0.0f, b1 = 0.0f, b2 = 1.0f, b3 = 1.0f;
            float sc = 0.0f, lb = -1.0f;
            if (s_ < cnt) {
                int i = kidx[s_];
                float4 bx = c_box[i];
                b0 = bx.x; b1 = bx.y; b2 = bx.z; b3 = bx.w;
                sc = c_val[i];
                lb = (float)c_cls[i];
            }
            int ob = (b * KOUT + s_) * 4;
            out[ob + 0] = b0; out[ob + 1] = b1;
            out[ob + 2] = b2; out[ob + 3] = b3;
            out[B_ * KOUT * 4 + b * KOUT + s_] = sc;   // scores
            out[B_ * KOUT * 5 + b * KOUT + s_] = lb;   // labels (as f32)
        }
    }
}

// ----------------------------------------------------------------
extern "C" void kernel_launch(void* const* d_in, const int* in_sizes, int n_in,
                              void* d_out, int out_size, void* d_ws, size_t ws_size,
                              hipStream_t stream) {
    const float* cls = (const float*)d_in[0];
    const float* loc = (const float*)d_in[1];
    const float* anc = (const float*)d_in[2];
    float* out = (float*)d_out;

    char* ws = (char*)d_ws;
    size_t off = 0;
    auto alloc = [&](size_t bytes) -> void* {
        void* p = ws + off;
        off += (bytes + 255) & ~(size_t)255;
        return p;
    };
    uint32_t* scores_u = (uint32_t*)alloc((size_t)B_ * A_ * 4);
    int*      classes  = (int*)     alloc((size_t)B_ * A_ * 4);
    float*    boxes    = (float*)   alloc((size_t)B_ * A_ * 4 * 4);
    uint64_t* keysg    = (uint64_t*)alloc((size_t)B_ * NKEY * 8);
    uint32_t* pcnt     = (uint32_t*)alloc((size_t)B_ * 4);

    hipMemsetAsync(pcnt, 0, (size_t)B_ * 4, stream);

    dim3 gD((A_ + GANCH - 1) / GANCH, B_);
    k_score_decode<<<gD, 256, 0, stream>>>(
        cls, loc, anc, scores_u, classes, boxes, keysg, pcnt);
    k_sort_nms<<<B_, 1024, 0, stream>>>(
        scores_u, pcnt, keysg, classes, boxes, out);
}